// Round 1
// baseline (993.673 us; speedup 1.0000x reference)
//
#include <hip/hip_runtime.h>
#include <hip/hip_bf16.h>
#include <stdint.h>

typedef __hip_bfloat16 bf16;
typedef __hip_bfloat162 bf162;

// ---------------- helpers ----------------

__device__ __forceinline__ void load8f(const float* __restrict__ p, float v[8]) {
    const float4 a = *(const float4*)p;
    const float4 b = *(const float4*)(p + 4);
    v[0] = a.x; v[1] = a.y; v[2] = a.z; v[3] = a.w;
    v[4] = b.x; v[5] = b.y; v[6] = b.z; v[7] = b.w;
}
__device__ __forceinline__ void load8f(const bf16* __restrict__ p, float v[8]) {
    const uint4 u = *(const uint4*)p;  // 8 bf16, 16B aligned by construction
    v[0] = __uint_as_float((u.x & 0xffffu) << 16); v[1] = __uint_as_float(u.x & 0xffff0000u);
    v[2] = __uint_as_float((u.y & 0xffffu) << 16); v[3] = __uint_as_float(u.y & 0xffff0000u);
    v[4] = __uint_as_float((u.z & 0xffffu) << 16); v[5] = __uint_as_float(u.z & 0xffff0000u);
    v[6] = __uint_as_float((u.w & 0xffffu) << 16); v[7] = __uint_as_float(u.w & 0xffff0000u);
}

__device__ __forceinline__ float2 load2f(const float* __restrict__ p) {
    return *(const float2*)p;
}
__device__ __forceinline__ float2 load2f(const bf16* __restrict__ p) {
    const unsigned int u = *(const unsigned int*)p;
    return make_float2(__uint_as_float((u & 0xffffu) << 16),
                       __uint_as_float(u & 0xffff0000u));
}

__device__ __forceinline__ void store4o(float* __restrict__ p, const float* v) {
    *(float4*)p = make_float4(v[0], v[1], v[2], v[3]);
}
__device__ __forceinline__ void store4o(bf16* __restrict__ p, const float* v) {
    bf162 a, b;
    a.x = __float2bfloat16(v[0]); a.y = __float2bfloat16(v[1]);
    b.x = __float2bfloat16(v[2]); b.y = __float2bfloat16(v[3]);
    *(bf162*)(p) = a;
    *(bf162*)(p + 2) = b;
}

// ---------------- CSR build ----------------

__global__ void hist_kernel(const int* __restrict__ dst, int* __restrict__ cnt, int E) {
    int e = blockIdx.x * blockDim.x + threadIdx.x;
    if (e < E) atomicAdd(&cnt[dst[e]], 1);
}

// single-block exclusive scan: 1024 threads, each owns a contiguous chunk
__global__ void scan_kernel(const int* __restrict__ deg, int* __restrict__ rp, int N) {
    __shared__ int tot[1024];
    const int t = threadIdx.x;
    const int C = (N + 1023) / 1024;
    const int beg = t * C;
    const int end = min(beg + C, N);
    int sum = 0;
    for (int i = beg; i < end; ++i) sum += deg[i];
    tot[t] = sum;
    __syncthreads();
    // Hillis-Steele inclusive scan over 1024 partials
    for (int off = 1; off < 1024; off <<= 1) {
        int v = (t >= off) ? tot[t - off] : 0;
        __syncthreads();
        tot[t] += v;
        __syncthreads();
    }
    int run = tot[t] - sum;  // exclusive offset for this chunk
    for (int i = beg; i < end; ++i) { rp[i] = run; run += deg[i]; }
    if (end == N) rp[N] = run;  // threads past the data write the same grand total — benign
}

__global__ void fill_kernel(const int* __restrict__ src, const int* __restrict__ dst,
                            const int* __restrict__ rp, int* __restrict__ cur,
                            int* __restrict__ col, int E) {
    int e = blockIdx.x * blockDim.x + threadIdx.x;
    if (e < E) {
        int d = dst[e];
        int pos = rp[d] + atomicAdd(&cur[d], 1);
        col[pos] = src[e];
    }
}

// ---------------- aggregation (CSR, atomic-free) ----------------
// one wave (64 lanes) per node; each lane owns 2 features (4B bf16x2 / 8B f32x2 loads)

template <typename T>
__global__ __launch_bounds__(256)
void agg_kernel(const T* __restrict__ h, const int* __restrict__ rp,
                const int* __restrict__ col, bf16* __restrict__ agg, int N) {
    const int lane = threadIdx.x & 63;
    const int wid  = threadIdx.x >> 6;
    const int node = blockIdx.x * 4 + wid;
    if (node >= N) return;
    const int beg = rp[node], end = rp[node + 1];
    const int f = lane * 2;
    float2 acc = make_float2(0.f, 0.f);
    int e = beg;
    for (; e + 2 <= end; e += 2) {
        const int s0 = col[e], s1 = col[e + 1];
        const float2 a = load2f(h + (size_t)s0 * 128 + f);
        const float2 b = load2f(h + (size_t)s1 * 128 + f);
        acc.x += a.x + b.x;
        acc.y += a.y + b.y;
    }
    if (e < end) {
        const int s0 = col[e];
        const float2 a = load2f(h + (size_t)s0 * 128 + f);
        acc.x += a.x;
        acc.y += a.y;
    }
    bf162 o;
    o.x = __float2bfloat16(acc.x);
    o.y = __float2bfloat16(acc.y);
    *(bf162*)(agg + (size_t)node * 128 + f) = o;
}

// ---------------- fused dual GEMM: out = A@Wrel + H@Wroot + b (+relu) ----------------
// tile: 64 rows x 128 cols per 256-thread block; K = 128+128 in 8 chunks of 32

template <typename T>
__device__ __forceinline__ void stage_in(const T* __restrict__ in, float* __restrict__ As,
                                         int row0, int k0, int M, int tid) {
    const int r = tid >> 2;            // 0..63
    const int seg = (tid & 3) * 8;     // 0,8,16,24
    const int row = row0 + r;
    float v[8];
    if (row < M) {
        load8f(in + (size_t)row * 128 + k0 + seg, v);
    } else {
#pragma unroll
        for (int j = 0; j < 8; ++j) v[j] = 0.f;
    }
    float* q = As + r * 33 + seg;
#pragma unroll
    for (int j = 0; j < 8; ++j) q[j] = v[j];
}

__device__ __forceinline__ void stage_w(const float* __restrict__ W, float* __restrict__ Ws,
                                        int k0, int tid) {
    const int kr = tid >> 3;           // 0..31
    const int t7 = tid & 7;
    const float* p = W + (size_t)(k0 + kr) * 128 + t7 * 4;
    float* q = Ws + kr * 128 + t7 * 4;
#pragma unroll
    for (int qq = 0; qq < 4; ++qq)
        *(float4*)(q + qq * 32) = *(const float4*)(p + qq * 32);
}

template <typename HT, typename OT, bool RELU>
__global__ __launch_bounds__(256)
void gemm_kernel(const bf16* __restrict__ A, const HT* __restrict__ H,
                 const float* __restrict__ Wrel, const float* __restrict__ Wroot,
                 const float* __restrict__ bias, OT* __restrict__ out, int M) {
    __shared__ float As[64 * 33];
    __shared__ float Ws[32 * 128];
    const int tid = threadIdx.x;
    const int tx = tid & 15;           // 16 col-groups
    const int ty = tid >> 4;           // 16 row-groups
    const int row0 = blockIdx.x * 64;

    float acc[4][8];
#pragma unroll
    for (int i = 0; i < 4; ++i)
#pragma unroll
        for (int j = 0; j < 8; ++j) acc[i][j] = 0.f;

#pragma unroll 1
    for (int chunk = 0; chunk < 8; ++chunk) {
        const int k0 = (chunk & 3) << 5;
        if (chunk < 4) {
            stage_in(A, As, row0, k0, M, tid);
            stage_w(Wrel, Ws, k0, tid);
        } else {
            stage_in(H, As, row0, k0, M, tid);
            stage_w(Wroot, Ws, k0, tid);
        }
        __syncthreads();
#pragma unroll
        for (int kk = 0; kk < 32; ++kk) {
            float a[4];
#pragma unroll
            for (int i = 0; i < 4; ++i) a[i] = As[(ty * 4 + i) * 33 + kk];
            const float4 w0 = *(const float4*)&Ws[kk * 128 + tx * 4];
            const float4 w1 = *(const float4*)&Ws[kk * 128 + 64 + tx * 4];
            const float w[8] = {w0.x, w0.y, w0.z, w0.w, w1.x, w1.y, w1.z, w1.w};
#pragma unroll
            for (int i = 0; i < 4; ++i)
#pragma unroll
                for (int j = 0; j < 8; ++j) acc[i][j] += a[i] * w[j];
        }
        __syncthreads();
    }

    float bv[8];
    {
        const float4 b0 = *(const float4*)&bias[tx * 4];
        const float4 b1 = *(const float4*)&bias[64 + tx * 4];
        bv[0] = b0.x; bv[1] = b0.y; bv[2] = b0.z; bv[3] = b0.w;
        bv[4] = b1.x; bv[5] = b1.y; bv[6] = b1.z; bv[7] = b1.w;
    }
#pragma unroll
    for (int i = 0; i < 4; ++i) {
        const int row = row0 + ty * 4 + i;
        if (row < M) {
            float v[8];
#pragma unroll
            for (int j = 0; j < 8; ++j) {
                float x = acc[i][j] + bv[j];
                if (RELU) x = fmaxf(x, 0.f);
                v[j] = x;
            }
            store4o(out + (size_t)row * 128 + tx * 4, v);
            store4o(out + (size_t)row * 128 + 64 + tx * 4, v + 4);
        }
    }
}

// ---------------- launch ----------------

extern "C" void kernel_launch(void* const* d_in, const int* in_sizes, int n_in,
                              void* d_out, int out_size, void* d_ws, size_t ws_size,
                              hipStream_t stream) {
    const float* x       = (const float*)d_in[0];
    const int*   ei      = (const int*)d_in[1];
    const float* w_rel1  = (const float*)d_in[2];
    const float* w_root1 = (const float*)d_in[3];
    const float* b1      = (const float*)d_in[4];
    const float* w_rel2  = (const float*)d_in[5];
    const float* w_root2 = (const float*)d_in[6];
    const float* b2      = (const float*)d_in[7];
    const float* w_rel3  = (const float*)d_in[8];
    const float* w_root3 = (const float*)d_in[9];
    const float* b3      = (const float*)d_in[10];
    float* out = (float*)d_out;

    const int N = in_sizes[0] / 128;
    const int E = in_sizes[1] / 2;
    const int* src = ei;
    const int* dst = ei + E;

    // workspace layout (~84 MB total)
    char* w = (char*)d_ws;
    auto alloc = [&](size_t bytes) {
        char* p = w;
        w += (bytes + 255) & ~(size_t)255;
        return p;
    };
    int*  col = (int*)alloc((size_t)E * 4);            // 6.4 MB
    int*  rp  = (int*)alloc((size_t)(N + 1) * 4);      // 0.4 MB
    int*  cnt = (int*)alloc((size_t)N * 4);            // 0.4 MB
    bf16* h1  = (bf16*)alloc((size_t)N * 128 * 2);     // 25.6 MB
    bf16* h2  = (bf16*)alloc((size_t)N * 128 * 2);     // 25.6 MB
    bf16* agg = (bf16*)alloc((size_t)N * 128 * 2);     // 25.6 MB

    const int edgeBlocks = (E + 255) / 256;
    const int aggBlocks  = (N + 3) / 4;
    const int gemmBlocks = (N + 63) / 64;

    // CSR by dst (rebuilt every call; same work each launch)
    hipMemsetAsync(cnt, 0, (size_t)N * 4, stream);
    hist_kernel<<<edgeBlocks, 256, 0, stream>>>(dst, cnt, E);
    scan_kernel<<<1, 1024, 0, stream>>>(cnt, rp, N);
    hipMemsetAsync(cnt, 0, (size_t)N * 4, stream);
    fill_kernel<<<edgeBlocks, 256, 0, stream>>>(src, dst, rp, cnt, col, E);

    // layer 1: agg from fp32 x, root input fp32 x, out bf16 h1, relu
    agg_kernel<float><<<aggBlocks, 256, 0, stream>>>(x, rp, col, agg, N);
    gemm_kernel<float, bf16, true><<<gemmBlocks, 256, 0, stream>>>(agg, x, w_rel1, w_root1, b1, h1, N);

    // layer 2: bf16 -> bf16, relu
    agg_kernel<bf16><<<aggBlocks, 256, 0, stream>>>(h1, rp, col, agg, N);
    gemm_kernel<bf16, bf16, true><<<gemmBlocks, 256, 0, stream>>>(agg, h1, w_rel2, w_root2, b2, h2, N);

    // layer 3: bf16 -> fp32 out, no relu
    agg_kernel<bf16><<<aggBlocks, 256, 0, stream>>>(h2, rp, col, agg, N);
    gemm_kernel<bf16, float, false><<<gemmBlocks, 256, 0, stream>>>(agg, h2, w_rel3, w_root3, b3, out, N);
}

// Round 2
// 586.674 us; speedup vs baseline: 1.6937x; 1.6937x over previous
//
#include <hip/hip_runtime.h>
#include <hip/hip_bf16.h>
#include <stdint.h>

typedef __hip_bfloat16 bf16;
typedef __hip_bfloat162 bf162;

typedef __attribute__((ext_vector_type(8))) short short8;   // 8 bf16 = 4 VGPRs
typedef __attribute__((ext_vector_type(4))) float floatx4;  // MFMA accumulator

// ---------------- helpers ----------------

__device__ __forceinline__ float2 load2f(const bf16* __restrict__ p) {
    const unsigned int u = *(const unsigned int*)p;
    return make_float2(__uint_as_float((u & 0xffffu) << 16),
                       __uint_as_float(u & 0xffff0000u));
}

// ---------------- prep: fp32 -> bf16 ----------------

__global__ __launch_bounds__(256)
void cvt_kernel(const float* __restrict__ x, bf16* __restrict__ y, int n4) {
    int i = blockIdx.x * 256 + threadIdx.x;
    if (i < n4) {
        float4 v = ((const float4*)x)[i];
        bf162 a, b;
        a.x = __float2bfloat16(v.x); a.y = __float2bfloat16(v.y);
        b.x = __float2bfloat16(v.z); b.y = __float2bfloat16(v.w);
        ((bf162*)y)[i * 2]     = a;
        ((bf162*)y)[i * 2 + 1] = b;
    }
}

// weights pre-swizzled to B-fragment layout for mfma_f32_16x16x32_bf16:
// wsw[((kt*8+ct)*64+lane)*8 + j] = W[kt*32 + (lane>>4)*8 + j][ct*16 + (lane&15)]
// where W = concat_k(w_rel, w_root), 256x128 row-major.
__global__ __launch_bounds__(256)
void prep_w_kernel(const float* __restrict__ wrel, const float* __restrict__ wroot,
                   bf16* __restrict__ wsw) {
    int t = blockIdx.x * 256 + threadIdx.x;       // 0..4095
    if (t >= 4096) return;
    const int lane = t & 63;
    const int ct   = (t >> 6) & 7;
    const int kt   = t >> 9;
    const int kbase = kt * 32 + (lane >> 4) * 8;
    const int n     = ct * 16 + (lane & 15);
    bf16* q = wsw + (size_t)t * 8;
#pragma unroll
    for (int j = 0; j < 8; ++j) {
        const int k = kbase + j;
        const float v = (k < 128) ? wrel[k * 128 + n] : wroot[(k - 128) * 128 + n];
        q[j] = __float2bfloat16(v);
    }
}

// ---------------- CSR build ----------------

__global__ void hist_kernel(const int* __restrict__ dst, int* __restrict__ cnt, int E) {
    int e = blockIdx.x * blockDim.x + threadIdx.x;
    if (e < E) atomicAdd(&cnt[dst[e]], 1);
}

// phase 1: per-block (256 elems) exclusive scan into rp, block total into bsum
__global__ __launch_bounds__(256)
void scan1_kernel(const int* __restrict__ deg, int* __restrict__ rp,
                  int* __restrict__ bsum, int N) {
    __shared__ int s[256];
    const int tid = threadIdx.x;
    const int i = blockIdx.x * 256 + tid;
    const int d = (i < N) ? deg[i] : 0;
    s[tid] = d;
    __syncthreads();
    for (int off = 1; off < 256; off <<= 1) {
        int u = (tid >= off) ? s[tid - off] : 0;
        __syncthreads();
        s[tid] += u;
        __syncthreads();
    }
    if (i < N) rp[i] = s[tid] - d;                // exclusive within block
    if (tid == 255) bsum[blockIdx.x] = s[255];    // block total
}

// phase 2: single block scans the (<=512) block totals -> exclusive
__global__ __launch_bounds__(512)
void scan2_kernel(int* __restrict__ bsum, int G) {
    __shared__ int s[512];
    const int tid = threadIdx.x;
    const int d = (tid < G) ? bsum[tid] : 0;
    s[tid] = d;
    __syncthreads();
    for (int off = 1; off < 512; off <<= 1) {
        int u = (tid >= off) ? s[tid - off] : 0;
        __syncthreads();
        s[tid] += u;
        __syncthreads();
    }
    if (tid < G) bsum[tid] = s[tid] - d;          // exclusive block offset
}

// phase 3: add block offsets; write rp[N] = E
__global__ __launch_bounds__(256)
void scan3_kernel(int* __restrict__ rp, const int* __restrict__ bsum, int N, int E) {
    const int i = blockIdx.x * 256 + threadIdx.x;
    if (i < N) rp[i] += bsum[blockIdx.x];
    if (i == 0) rp[N] = E;
}

__global__ void fill_kernel(const int* __restrict__ src, const int* __restrict__ dst,
                            const int* __restrict__ rp, int* __restrict__ cur,
                            int* __restrict__ col, int E) {
    int e = blockIdx.x * blockDim.x + threadIdx.x;
    if (e < E) {
        int d = dst[e];
        int pos = rp[d] + atomicAdd(&cur[d], 1);
        col[pos] = src[e];
    }
}

// ---------------- aggregation (CSR, atomic-free, bf16) ----------------
// one wave per node; lane owns 2 features; 4-edge unroll for MLP

__global__ __launch_bounds__(256)
void agg_kernel(const bf16* __restrict__ h, const int* __restrict__ rp,
                const int* __restrict__ col, bf16* __restrict__ agg, int N) {
    const int lane = threadIdx.x & 63;
    const int wid  = threadIdx.x >> 6;
    const int node = blockIdx.x * 4 + wid;
    if (node >= N) return;
    const int beg = rp[node], end = rp[node + 1];
    const int f = lane * 2;
    float2 acc = make_float2(0.f, 0.f);
    int e = beg;
    for (; e + 4 <= end; e += 4) {
        const int s0 = col[e], s1 = col[e + 1], s2 = col[e + 2], s3 = col[e + 3];
        const float2 a = load2f(h + (size_t)s0 * 128 + f);
        const float2 b = load2f(h + (size_t)s1 * 128 + f);
        const float2 c = load2f(h + (size_t)s2 * 128 + f);
        const float2 d = load2f(h + (size_t)s3 * 128 + f);
        acc.x += (a.x + b.x) + (c.x + d.x);
        acc.y += (a.y + b.y) + (c.y + d.y);
    }
    for (; e < end; ++e) {
        const int s0 = col[e];
        const float2 a = load2f(h + (size_t)s0 * 128 + f);
        acc.x += a.x;
        acc.y += a.y;
    }
    bf162 o;
    o.x = __float2bfloat16(acc.x);
    o.y = __float2bfloat16(acc.y);
    *(bf162*)(agg + (size_t)node * 128 + f) = o;
}

// ---------------- MFMA dual GEMM: out = [agg|h] @ Wsw + b (+relu) ----------------
// block = 256 (4 waves); each wave: 16 rows x 128 cols; K = 256 in 8 steps of 32.
// A-frag: lane holds A[m=lane&15][k=quad*8+j] -> 16B contiguous global load.
// B-frag: pre-swizzled wsw, 16B contiguous per lane, L2-resident (64 KB).
// C/D: col = lane&15, row = quad*4 + reg  (verified layout).

template <bool RELU, typename OT>
__global__ __launch_bounds__(256)
void mfma_gemm_kernel(const bf16* __restrict__ Aagg, const bf16* __restrict__ Hroot,
                      const bf16* __restrict__ wsw, const float* __restrict__ bias,
                      OT* __restrict__ out, int M) {
    const int tid  = threadIdx.x;
    const int lane = tid & 63;
    const int wave = tid >> 6;
    const int l15  = lane & 15;
    const int quad = lane >> 4;

    const int row_a = blockIdx.x * 64 + wave * 16 + l15;
    const bool rowok = row_a < M;

    floatx4 acc[8];
#pragma unroll
    for (int ct = 0; ct < 8; ++ct) acc[ct] = (floatx4){0.f, 0.f, 0.f, 0.f};

#pragma unroll
    for (int kt = 0; kt < 8; ++kt) {
        const bf16* Abase = (kt < 4) ? Aagg : Hroot;
        const int k0 = (kt & 3) * 32 + quad * 8;
        short8 afrag = (short8){0, 0, 0, 0, 0, 0, 0, 0};
        if (rowok) afrag = *(const short8*)(Abase + (size_t)row_a * 128 + k0);
#pragma unroll
        for (int ct = 0; ct < 8; ++ct) {
            const short8 bfrag = *(const short8*)(wsw + (size_t)((kt * 8 + ct) * 64 + lane) * 8);
            acc[ct] = __builtin_amdgcn_mfma_f32_16x16x32_bf16(afrag, bfrag, acc[ct], 0, 0, 0);
        }
    }

    const int row_o = blockIdx.x * 64 + wave * 16 + quad * 4;
#pragma unroll
    for (int ct = 0; ct < 8; ++ct) {
        const int colc = ct * 16 + l15;
        const float bv = bias[colc];
#pragma unroll
        for (int r = 0; r < 4; ++r) {
            const int row = row_o + r;
            if (row < M) {
                float v = acc[ct][r] + bv;
                if (RELU) v = fmaxf(v, 0.f);
                if constexpr (sizeof(OT) == 2)
                    ((bf16*)out)[(size_t)row * 128 + colc] = __float2bfloat16(v);
                else
                    ((float*)out)[(size_t)row * 128 + colc] = v;
            }
        }
    }
}

// ---------------- launch ----------------

extern "C" void kernel_launch(void* const* d_in, const int* in_sizes, int n_in,
                              void* d_out, int out_size, void* d_ws, size_t ws_size,
                              hipStream_t stream) {
    const float* x       = (const float*)d_in[0];
    const int*   ei      = (const int*)d_in[1];
    const float* w_rel1  = (const float*)d_in[2];
    const float* w_root1 = (const float*)d_in[3];
    const float* b1      = (const float*)d_in[4];
    const float* w_rel2  = (const float*)d_in[5];
    const float* w_root2 = (const float*)d_in[6];
    const float* b2      = (const float*)d_in[7];
    const float* w_rel3  = (const float*)d_in[8];
    const float* w_root3 = (const float*)d_in[9];
    const float* b3      = (const float*)d_in[10];
    float* out = (float*)d_out;

    const int N = in_sizes[0] / 128;
    const int E = in_sizes[1] / 2;
    const int* src = ei;
    const int* dst = ei + E;

    // workspace layout (~84.2 MB)
    char* w = (char*)d_ws;
    auto alloc = [&](size_t bytes) {
        char* p = w;
        w += (bytes + 255) & ~(size_t)255;
        return p;
    };
    int*  col  = (int*)alloc((size_t)E * 4);            // 6.4 MB
    int*  rp   = (int*)alloc((size_t)(N + 1) * 4);      // 0.4 MB
    int*  cnt  = (int*)alloc((size_t)N * 4);            // 0.4 MB
    bf16* h1   = (bf16*)alloc((size_t)N * 128 * 2);     // 25.6 MB
    bf16* xbf  = (bf16*)alloc((size_t)N * 128 * 2);     // 25.6 MB (reused as h2)
    bf16* agg  = (bf16*)alloc((size_t)N * 128 * 2);     // 25.6 MB
    bf16* wsw1 = (bf16*)alloc(32768 * 2);               // 64 KB
    bf16* wsw2 = (bf16*)alloc(32768 * 2);
    bf16* wsw3 = (bf16*)alloc(32768 * 2);
    bf16* h2   = xbf;  // layer-2 output overwrites xbf (last read at layer-1 gemm)
    int*  bsum = col;  // scan scratch aliases col (col written only after scan)

    const int edgeBlocks = (E + 255) / 256;
    const int aggBlocks  = (N + 3) / 4;
    const int gemmBlocks = (N + 63) / 64;
    const int scanBlocks = (N + 255) / 256;   // 391 <= 512
    const int cvtBlocks  = (N * 32 + 255) / 256;

    // prep: x -> bf16, weights -> swizzled bf16 B-fragments
    cvt_kernel<<<cvtBlocks, 256, 0, stream>>>(x, xbf, N * 32);
    prep_w_kernel<<<16, 256, 0, stream>>>(w_rel1, w_root1, wsw1);
    prep_w_kernel<<<16, 256, 0, stream>>>(w_rel2, w_root2, wsw2);
    prep_w_kernel<<<16, 256, 0, stream>>>(w_rel3, w_root3, wsw3);

    // CSR by dst
    hipMemsetAsync(cnt, 0, (size_t)N * 4, stream);
    hist_kernel<<<edgeBlocks, 256, 0, stream>>>(dst, cnt, E);
    scan1_kernel<<<scanBlocks, 256, 0, stream>>>(cnt, rp, bsum, N);
    scan2_kernel<<<1, 512, 0, stream>>>(bsum, scanBlocks);
    scan3_kernel<<<scanBlocks, 256, 0, stream>>>(rp, bsum, N, E);
    hipMemsetAsync(cnt, 0, (size_t)N * 4, stream);
    fill_kernel<<<edgeBlocks, 256, 0, stream>>>(src, dst, rp, cnt, col, E);

    // layer 1
    agg_kernel<<<aggBlocks, 256, 0, stream>>>(xbf, rp, col, agg, N);
    mfma_gemm_kernel<true, bf16><<<gemmBlocks, 256, 0, stream>>>(agg, xbf, wsw1, b1, h1, N);
    // layer 2
    agg_kernel<<<aggBlocks, 256, 0, stream>>>(h1, rp, col, agg, N);
    mfma_gemm_kernel<true, bf16><<<gemmBlocks, 256, 0, stream>>>(agg, h1, wsw2, b2, h2, N);
    // layer 3
    agg_kernel<<<aggBlocks, 256, 0, stream>>>(h2, rp, col, agg, N);
    mfma_gemm_kernel<false, float><<<gemmBlocks, 256, 0, stream>>>(agg, h2, wsw3, b3, out, N);
}

// Round 3
// 505.189 us; speedup vs baseline: 1.9669x; 1.1613x over previous
//
#include <hip/hip_runtime.h>
#include <hip/hip_bf16.h>
#include <stdint.h>

typedef __hip_bfloat16 bf16;
typedef __hip_bfloat162 bf162;

typedef __attribute__((ext_vector_type(8))) short short8;   // 8 bf16 = 4 VGPRs
typedef __attribute__((ext_vector_type(4))) float floatx4;  // MFMA accumulator

#define BSH   8        // bucket = 256 nodes
#define BSZ   256
#define CHUNK 8192     // edges per sort block
#define NBMAX 512      // max buckets supported (N <= 131072)

// ---------------- helpers ----------------

__device__ __forceinline__ float2 load2f(const bf16* __restrict__ p) {
    const unsigned int u = *(const unsigned int*)p;
    return make_float2(__uint_as_float((u & 0xffffu) << 16),
                       __uint_as_float(u & 0xffff0000u));
}

// ---------------- prep: fp32 -> bf16 ----------------

__global__ __launch_bounds__(256)
void cvt_kernel(const float* __restrict__ x, bf16* __restrict__ y, int n4) {
    int i = blockIdx.x * 256 + threadIdx.x;
    if (i < n4) {
        float4 v = ((const float4*)x)[i];
        bf162 a, b;
        a.x = __float2bfloat16(v.x); a.y = __float2bfloat16(v.y);
        b.x = __float2bfloat16(v.z); b.y = __float2bfloat16(v.w);
        ((bf162*)y)[i * 2]     = a;
        ((bf162*)y)[i * 2 + 1] = b;
    }
}

// weights pre-swizzled to B-fragment layout for mfma_f32_16x16x32_bf16:
// wsw[((kt*8+ct)*64+lane)*8 + j] = W[kt*32 + (lane>>4)*8 + j][ct*16 + (lane&15)]
// where W = concat_k(w_rel, w_root), 256x128 row-major.
__global__ __launch_bounds__(256)
void prep_w_kernel(const float* __restrict__ wrel, const float* __restrict__ wroot,
                   bf16* __restrict__ wsw) {
    int t = blockIdx.x * 256 + threadIdx.x;       // 0..4095
    if (t >= 4096) return;
    const int lane = t & 63;
    const int ct   = (t >> 6) & 7;
    const int kt   = t >> 9;
    const int kbase = kt * 32 + (lane >> 4) * 8;
    const int n     = ct * 16 + (lane & 15);
    bf16* q = wsw + (size_t)t * 8;
#pragma unroll
    for (int j = 0; j < 8; ++j) {
        const int k = kbase + j;
        const float v = (k < 128) ? wrel[k * 128 + n] : wroot[(k - 128) * 128 + n];
        q[j] = __float2bfloat16(v);
    }
}

// ---------------- CSR build: two-level counting sort ----------------
// phase A: per-chunk LDS histogram over coarse buckets -> T[u*GB + b]

__global__ __launch_bounds__(256)
void bhist_kernel(const int* __restrict__ dst, int* __restrict__ T,
                  int E, int NB, int GB) {
    __shared__ int lh[NBMAX];
    const int b = blockIdx.x;
    for (int u = threadIdx.x; u < NB; u += 256) lh[u] = 0;
    __syncthreads();
    const int beg = b * CHUNK, end = min(beg + CHUNK, E);
    for (int e = beg + threadIdx.x; e < end; e += 256)
        atomicAdd(&lh[dst[e] >> BSH], 1);
    __syncthreads();
    for (int u = threadIdx.x; u < NB; u += 256)
        T[u * GB + b] = lh[u];
}

// generic 3-phase exclusive scan (in-place safe: each block reads its range
// before writing it)

__global__ __launch_bounds__(256)
void scan1_kernel(const int* __restrict__ deg, int* __restrict__ rp,
                  int* __restrict__ bsum, int n) {
    __shared__ int s[256];
    const int tid = threadIdx.x;
    const int i = blockIdx.x * 256 + tid;
    const int d = (i < n) ? deg[i] : 0;
    s[tid] = d;
    __syncthreads();
    for (int off = 1; off < 256; off <<= 1) {
        int u = (tid >= off) ? s[tid - off] : 0;
        __syncthreads();
        s[tid] += u;
        __syncthreads();
    }
    if (i < n) rp[i] = s[tid] - d;
    if (tid == 255) bsum[blockIdx.x] = s[255];
}

__global__ __launch_bounds__(512)
void scan2_kernel(int* __restrict__ bsum, int G) {
    __shared__ int s[512];
    const int tid = threadIdx.x;
    const int d = (tid < G) ? bsum[tid] : 0;
    s[tid] = d;
    __syncthreads();
    for (int off = 1; off < 512; off <<= 1) {
        int u = (tid >= off) ? s[tid - off] : 0;
        __syncthreads();
        s[tid] += u;
        __syncthreads();
    }
    if (tid < G) bsum[tid] = s[tid] - d;
}

__global__ __launch_bounds__(256)
void scan3_kernel(int* __restrict__ rp, const int* __restrict__ bsum, int n) {
    const int i = blockIdx.x * 256 + threadIdx.x;
    if (i < n) rp[i] += bsum[blockIdx.x];
}

// phase B: scatter edges into bucket-grouped ebuf, packed (src<<8)|dst_lo

__global__ __launch_bounds__(256)
void bscatter_kernel(const int* __restrict__ src, const int* __restrict__ dst,
                     const int* __restrict__ T, int* __restrict__ ebuf,
                     int E, int NB, int GB) {
    __shared__ int lofs[NBMAX];
    const int b = blockIdx.x;
    for (int u = threadIdx.x; u < NB; u += 256)
        lofs[u] = T[u * GB + b];
    __syncthreads();
    const int beg = b * CHUNK, end = min(beg + CHUNK, E);
    for (int e = beg + threadIdx.x; e < end; e += 256) {
        const int d = dst[e];
        const int u = d >> BSH;
        const int pos = atomicAdd(&lofs[u], 1);
        ebuf[pos] = (src[e] << BSH) | (d & (BSZ - 1));
    }
}

// phase C: one block per bucket; local counting sort -> rp + col

__global__ __launch_bounds__(256)
void bbuild_kernel(const int* __restrict__ T, const int* __restrict__ ebuf,
                   int* __restrict__ rp, int* __restrict__ col,
                   int E, int N, int NB, int GB) {
    __shared__ int s[256];
    __shared__ int lrank[256];
    const int u = blockIdx.x;
    const int tid = threadIdx.x;
    const int beg = T[u * GB];
    const int end = (u + 1 < NB) ? T[(u + 1) * GB] : E;

    lrank[tid] = 0;
    __syncthreads();
    for (int e = beg + tid; e < end; e += 256)
        atomicAdd(&lrank[ebuf[e] & (BSZ - 1)], 1);
    __syncthreads();
    const int cntv = lrank[tid];
    s[tid] = cntv;
    __syncthreads();
    for (int off = 1; off < 256; off <<= 1) {
        int v = (tid >= off) ? s[tid - off] : 0;
        __syncthreads();
        s[tid] += v;
        __syncthreads();
    }
    const int excl = s[tid] - cntv;               // exclusive within bucket
    const int node = u * BSZ + tid;
    if (node < N) rp[node] = beg + excl;
    if (u == NB - 1 && tid == 0) rp[N] = E;
    lrank[tid] = beg + excl;                      // running write cursor
    __syncthreads();
    for (int e = beg + tid; e < end; e += 256) {
        const int p = ebuf[e];
        const int pos = atomicAdd(&lrank[p & (BSZ - 1)], 1);
        col[pos] = p >> BSH;
    }
}

// ---------------- aggregation (CSR, atomic-free, bf16) ----------------

__global__ __launch_bounds__(256)
void agg_kernel(const bf16* __restrict__ h, const int* __restrict__ rp,
                const int* __restrict__ col, bf16* __restrict__ agg, int N) {
    const int lane = threadIdx.x & 63;
    const int wid  = threadIdx.x >> 6;
    const int node = blockIdx.x * 4 + wid;
    if (node >= N) return;
    const int beg = rp[node], end = rp[node + 1];
    const int f = lane * 2;
    float2 acc = make_float2(0.f, 0.f);
    int e = beg;
    for (; e + 4 <= end; e += 4) {
        const int s0 = col[e], s1 = col[e + 1], s2 = col[e + 2], s3 = col[e + 3];
        const float2 a = load2f(h + (size_t)s0 * 128 + f);
        const float2 b = load2f(h + (size_t)s1 * 128 + f);
        const float2 c = load2f(h + (size_t)s2 * 128 + f);
        const float2 d = load2f(h + (size_t)s3 * 128 + f);
        acc.x += (a.x + b.x) + (c.x + d.x);
        acc.y += (a.y + b.y) + (c.y + d.y);
    }
    for (; e < end; ++e) {
        const int s0 = col[e];
        const float2 a = load2f(h + (size_t)s0 * 128 + f);
        acc.x += a.x;
        acc.y += a.y;
    }
    bf162 o;
    o.x = __float2bfloat16(acc.x);
    o.y = __float2bfloat16(acc.y);
    *(bf162*)(agg + (size_t)node * 128 + f) = o;
}

// ---------------- MFMA dual GEMM: out = [agg|h] @ Wsw + b (+relu) ----------------

template <bool RELU, typename OT>
__global__ __launch_bounds__(256)
void mfma_gemm_kernel(const bf16* __restrict__ Aagg, const bf16* __restrict__ Hroot,
                      const bf16* __restrict__ wsw, const float* __restrict__ bias,
                      OT* __restrict__ out, int M) {
    const int tid  = threadIdx.x;
    const int lane = tid & 63;
    const int wave = tid >> 6;
    const int l15  = lane & 15;
    const int quad = lane >> 4;

    const int row_a = blockIdx.x * 64 + wave * 16 + l15;
    const bool rowok = row_a < M;

    floatx4 acc[8];
#pragma unroll
    for (int ct = 0; ct < 8; ++ct) acc[ct] = (floatx4){0.f, 0.f, 0.f, 0.f};

#pragma unroll
    for (int kt = 0; kt < 8; ++kt) {
        const bf16* Abase = (kt < 4) ? Aagg : Hroot;
        const int k0 = (kt & 3) * 32 + quad * 8;
        short8 afrag = (short8){0, 0, 0, 0, 0, 0, 0, 0};
        if (rowok) afrag = *(const short8*)(Abase + (size_t)row_a * 128 + k0);
#pragma unroll
        for (int ct = 0; ct < 8; ++ct) {
            const short8 bfrag = *(const short8*)(wsw + (size_t)((kt * 8 + ct) * 64 + lane) * 8);
            acc[ct] = __builtin_amdgcn_mfma_f32_16x16x32_bf16(afrag, bfrag, acc[ct], 0, 0, 0);
        }
    }

    const int row_o = blockIdx.x * 64 + wave * 16 + quad * 4;
#pragma unroll
    for (int ct = 0; ct < 8; ++ct) {
        const int colc = ct * 16 + l15;
        const float bv = bias[colc];
#pragma unroll
        for (int r = 0; r < 4; ++r) {
            const int row = row_o + r;
            if (row < M) {
                float v = acc[ct][r] + bv;
                if (RELU) v = fmaxf(v, 0.f);
                if constexpr (sizeof(OT) == 2)
                    ((bf16*)out)[(size_t)row * 128 + colc] = __float2bfloat16(v);
                else
                    ((float*)out)[(size_t)row * 128 + colc] = v;
            }
        }
    }
}

// ---------------- launch ----------------

extern "C" void kernel_launch(void* const* d_in, const int* in_sizes, int n_in,
                              void* d_out, int out_size, void* d_ws, size_t ws_size,
                              hipStream_t stream) {
    const float* x       = (const float*)d_in[0];
    const int*   ei      = (const int*)d_in[1];
    const float* w_rel1  = (const float*)d_in[2];
    const float* w_root1 = (const float*)d_in[3];
    const float* b1      = (const float*)d_in[4];
    const float* w_rel2  = (const float*)d_in[5];
    const float* w_root2 = (const float*)d_in[6];
    const float* b2      = (const float*)d_in[7];
    const float* w_rel3  = (const float*)d_in[8];
    const float* w_root3 = (const float*)d_in[9];
    const float* b3      = (const float*)d_in[10];
    float* out = (float*)d_out;

    const int N = in_sizes[0] / 128;
    const int E = in_sizes[1] / 2;
    const int* src = ei;
    const int* dst = ei + E;

    // workspace layout (~84 MB)
    char* w = (char*)d_ws;
    auto alloc = [&](size_t bytes) {
        char* p = w;
        w += (bytes + 255) & ~(size_t)255;
        return p;
    };
    int*  col  = (int*)alloc((size_t)E * 4);            // 6.4 MB
    int*  rp   = (int*)alloc((size_t)(N + 1) * 4);      // 0.4 MB
    bf16* h1   = (bf16*)alloc((size_t)N * 128 * 2);     // 25.6 MB
    bf16* xbf  = (bf16*)alloc((size_t)N * 128 * 2);     // 25.6 MB (reused as h2)
    bf16* agg  = (bf16*)alloc((size_t)N * 128 * 2);     // 25.6 MB
    bf16* wsw1 = (bf16*)alloc(32768 * 2);               // 64 KB
    bf16* wsw2 = (bf16*)alloc(32768 * 2);
    bf16* wsw3 = (bf16*)alloc(32768 * 2);
    bf16* h2   = xbf;       // layer-2 output overwrites xbf (last read: layer-1 gemm)
    // CSR-build scratch aliases buffers written only AFTER the build completes:
    int*  T    = (int*)h1;                  // NB*GB ints (~306 KB) in h1's space
    int*  bsum = (int*)(h1 + 1024 * 1024);  // scan partials, past T
    int*  ebuf = (int*)agg;                 // E ints (6.4 MB) in agg's space

    const int NB = (N + BSZ - 1) / BSZ;        // 391 buckets
    const int GB = (E + CHUNK - 1) / CHUNK;    // 196 sort blocks
    const int nT = NB * GB;                    // 76,636
    const int scanTBlocks = (nT + 255) / 256;  // 300 <= 512

    const int aggBlocks  = (N + 3) / 4;
    const int gemmBlocks = (N + 63) / 64;
    const int cvtBlocks  = (N * 32 + 255) / 256;

    // prep: x -> bf16, weights -> swizzled bf16 B-fragments
    cvt_kernel<<<cvtBlocks, 256, 0, stream>>>(x, xbf, N * 32);
    prep_w_kernel<<<16, 256, 0, stream>>>(w_rel1, w_root1, wsw1);
    prep_w_kernel<<<16, 256, 0, stream>>>(w_rel2, w_root2, wsw2);
    prep_w_kernel<<<16, 256, 0, stream>>>(w_rel3, w_root3, wsw3);

    // CSR by dst: two-level counting sort (no global atomics, no memsets)
    bhist_kernel<<<GB, 256, 0, stream>>>(dst, T, E, NB, GB);
    scan1_kernel<<<scanTBlocks, 256, 0, stream>>>(T, T, bsum, nT);
    scan2_kernel<<<1, 512, 0, stream>>>(bsum, scanTBlocks);
    scan3_kernel<<<scanTBlocks, 256, 0, stream>>>(T, bsum, nT);
    bscatter_kernel<<<GB, 256, 0, stream>>>(src, dst, T, ebuf, E, NB, GB);
    bbuild_kernel<<<NB, 256, 0, stream>>>(T, ebuf, rp, col, E, N, NB, GB);

    // layer 1
    agg_kernel<<<aggBlocks, 256, 0, stream>>>(xbf, rp, col, agg, N);
    mfma_gemm_kernel<true, bf16><<<gemmBlocks, 256, 0, stream>>>(agg, xbf, wsw1, b1, h1, N);
    // layer 2
    agg_kernel<<<aggBlocks, 256, 0, stream>>>(h1, rp, col, agg, N);
    mfma_gemm_kernel<true, bf16><<<gemmBlocks, 256, 0, stream>>>(agg, h1, wsw2, b2, h2, N);
    // layer 3
    agg_kernel<<<aggBlocks, 256, 0, stream>>>(h2, rp, col, agg, N);
    mfma_gemm_kernel<false, float><<<gemmBlocks, 256, 0, stream>>>(agg, h2, wsw3, b3, out, N);
}